// Round 9
// baseline (176.133 us; speedup 1.0000x reference)
//
#include <hip/hip_runtime.h>

typedef unsigned short u16;
typedef short s16x8 __attribute__((ext_vector_type(8)));
typedef float f32x4 __attribute__((ext_vector_type(4)));

#define NB 16
#define DMODEL 384
#define SDIM 64
#define LSEQ 4096
#define C3S 192

__device__ __forceinline__ float b2f(u16 u) {
    union { unsigned int i; float f; } v; v.i = ((unsigned int)u) << 16; return v.f;
}
__device__ __forceinline__ u16 f2b(float f) {
    union { float ff; unsigned int i; } v; v.ff = f;
    unsigned int x = v.i;
    unsigned int r = (x + 0x7fffu + ((x >> 16) & 1u)) >> 16;
    return (u16)r;
}

// ---------------- kcvt: xbT[b,l,d] = bf16(x^T) ----------------
__global__ __launch_bounds__(256) void kcvt(const float* __restrict__ x,
                                            u16* __restrict__ xbT) {
    __shared__ __align__(16) u16 T[64][72];
    const int t = threadIdx.x;
    const int l0 = blockIdx.x * 64;
    const int d0 = blockIdx.y * 64;
    const int b = blockIdx.z;
    const int dr = t >> 2;
    const int lo = (t & 3) * 16;
    const float* xp = x + ((size_t)(b * DMODEL + d0 + dr)) * LSEQ + l0 + lo;
    float4 x0 = *reinterpret_cast<const float4*>(xp + 0);
    float4 x1 = *reinterpret_cast<const float4*>(xp + 4);
    float4 x2 = *reinterpret_cast<const float4*>(xp + 8);
    float4 x3 = *reinterpret_cast<const float4*>(xp + 12);
    s16x8 va, vb;
    va[0] = (short)f2b(x0.x); va[1] = (short)f2b(x0.y); va[2] = (short)f2b(x0.z); va[3] = (short)f2b(x0.w);
    va[4] = (short)f2b(x1.x); va[5] = (short)f2b(x1.y); va[6] = (short)f2b(x1.z); va[7] = (short)f2b(x1.w);
    vb[0] = (short)f2b(x2.x); vb[1] = (short)f2b(x2.y); vb[2] = (short)f2b(x2.z); vb[3] = (short)f2b(x2.w);
    vb[4] = (short)f2b(x3.x); vb[5] = (short)f2b(x3.y); vb[6] = (short)f2b(x3.z); vb[7] = (short)f2b(x3.w);
    *reinterpret_cast<s16x8*>(&T[dr][lo + 0]) = va;
    *reinterpret_cast<s16x8*>(&T[dr][lo + 8]) = vb;
    __syncthreads();
    const int lr = t >> 2;
    const int dof = (t & 3) * 16;
    s16x8 wa, wb;
    #pragma unroll
    for (int j = 0; j < 8; ++j) {
        wa[j] = (short)T[dof + j][lr];
        wb[j] = (short)T[dof + 8 + j][lr];
    }
    u16* xtp = xbT + ((size_t)(b * LSEQ + l0 + lr)) * DMODEL + d0 + dof;
    *reinterpret_cast<s16x8*>(xtp + 0) = wa;
    *reinterpret_cast<s16x8*>(xtp + 8) = wb;
}

// ---------------- k1: bcdt = W_bcdt x (MFMA, 512 thr, all 192 o per block) ---------
// grid (16 ltiles of 256, 16 b), block 512 = 8 waves (4 o-waves x 2 l-waves)
__global__ __launch_bounds__(512) void k1_mfma(const u16* __restrict__ xbT,
                                               const float* __restrict__ Wb,
                                               u16* __restrict__ rawbc,
                                               float* __restrict__ rawdt) {
    __shared__ __align__(16) short As[192 * 40];
    __shared__ __align__(16) short Bs[256 * 40];
    const int t = threadIdx.x;
    const int l0 = blockIdx.x * 256;
    const int b = blockIdx.y;
    const int lane = t & 63;
    const int w = t >> 6;
    const int wm = w >> 1, wn = w & 1;     // wm 0..3 (o), wn 0..1 (l)
    const int lm = lane & 15, kg = lane >> 4;
    f32x4 acc[3][8];
    #pragma unroll
    for (int i = 0; i < 3; ++i)
        #pragma unroll
        for (int j = 0; j < 8; ++j) acc[i][j] = (f32x4){0.f, 0.f, 0.f, 0.f};

    const u16* bp = xbT + ((size_t)(b * LSEQ + l0)) * DMODEL;
    const int brow = t >> 1;               // 0..255
    const int boff = (t & 1) * 16;         // 0,16

    for (int kc = 0; kc < DMODEL; kc += 32) {
        if (t < 192) {
            const float* wp = Wb + (size_t)t * DMODEL + kc;
            #pragma unroll
            for (int c = 0; c < 4; ++c) {
                float4 w0 = *reinterpret_cast<const float4*>(wp + c * 8);
                float4 w1 = *reinterpret_cast<const float4*>(wp + c * 8 + 4);
                s16x8 av;
                av[0] = (short)f2b(w0.x); av[1] = (short)f2b(w0.y); av[2] = (short)f2b(w0.z); av[3] = (short)f2b(w0.w);
                av[4] = (short)f2b(w1.x); av[5] = (short)f2b(w1.y); av[6] = (short)f2b(w1.z); av[7] = (short)f2b(w1.w);
                *reinterpret_cast<s16x8*>(&As[t * 40 + c * 8]) = av;
            }
        }
        {
            const u16* src = bp + (size_t)brow * DMODEL + kc + boff;
            s16x8 bv0 = *reinterpret_cast<const s16x8*>(src);
            s16x8 bv1 = *reinterpret_cast<const s16x8*>(src + 8);
            *reinterpret_cast<s16x8*>(&Bs[brow * 40 + boff]) = bv0;
            *reinterpret_cast<s16x8*>(&Bs[brow * 40 + boff + 8]) = bv1;
        }
        __syncthreads();
        s16x8 af[3], bf[8];
        #pragma unroll
        for (int i = 0; i < 3; ++i)
            af[i] = *reinterpret_cast<s16x8*>(&As[(wm * 48 + i * 16 + lm) * 40 + kg * 8]);
        #pragma unroll
        for (int j = 0; j < 8; ++j)
            bf[j] = *reinterpret_cast<s16x8*>(&Bs[(wn * 128 + j * 16 + lm) * 40 + kg * 8]);
        #pragma unroll
        for (int i = 0; i < 3; ++i)
            #pragma unroll
            for (int j = 0; j < 8; ++j)
                acc[i][j] = __builtin_amdgcn_mfma_f32_16x16x32_bf16(af[i], bf[j], acc[i][j], 0, 0, 0);
        __syncthreads();
    }
    #pragma unroll
    for (int i = 0; i < 3; ++i) {
        #pragma unroll
        for (int j = 0; j < 8; ++j) {
            #pragma unroll
            for (int r = 0; r < 4; ++r) {
                int o = wm * 48 + i * 16 + kg * 4 + r;
                int l = l0 + wn * 128 + j * 16 + lm;
                float val = acc[i][j][r];
                if (o < 128) rawbc[((size_t)b * 128 + o) * LSEQ + l] = f2b(val);
                else         rawdt[((size_t)b * 64 + (o - 128)) * LSEQ + l] = val;
            }
        }
    }
}

// ---------------- k2c: CMB[b,s,l] = bf16(dwconv3x3(rawbc ch 64+s)) ----------------
__global__ __launch_bounds__(256) void k2c_cm(const u16* __restrict__ rawbc,
                                              const float* __restrict__ Wdw,
                                              u16* __restrict__ CMB) {
    const int t = threadIdx.x;
    const int rg = blockIdx.x;
    const int c = blockIdx.y;
    const int b = blockIdx.z;
    const int row = rg * 4 + (t >> 6);
    const int col = t & 63;
    float w[9];
    #pragma unroll
    for (int k = 0; k < 9; ++k) w[k] = Wdw[(64 + c) * 9 + k];
    const u16* ip = rawbc + ((size_t)b * 128 + 64 + c) * LSEQ;
    float acc = 0.f;
    #pragma unroll
    for (int dy = -1; dy <= 1; ++dy) {
        int r = row + dy;
        if (r < 0 || r > 63) continue;
        #pragma unroll
        for (int dx = -1; dx <= 1; ++dx) {
            int cc = col + dx;
            if (cc < 0 || cc > 63) continue;
            acc = fmaf(w[(dy + 1) * 3 + (dx + 1)], b2f(ip[r * 64 + cc]), acc);
        }
    }
    CMB[((size_t)b * SDIM + c) * LSEQ + row * 64 + col] = f2b(acc);
}

// ---------------- kcmT: CmT[b,l,s] = CMB^T (bf16) ----------------
__global__ __launch_bounds__(256) void kcmT(const u16* __restrict__ CMB,
                                            u16* __restrict__ CmT) {
    __shared__ __align__(16) u16 T[64][72];
    const int t = threadIdx.x;
    const int l0 = blockIdx.x * 64;
    const int b = blockIdx.y;
    const int sr = t >> 2;
    const int lo = (t & 3) * 16;
    const u16* ip = CMB + ((size_t)(b * SDIM + sr)) * LSEQ + l0 + lo;
    s16x8 va = *reinterpret_cast<const s16x8*>(ip);
    s16x8 vb = *reinterpret_cast<const s16x8*>(ip + 8);
    *reinterpret_cast<s16x8*>(&T[sr][lo + 0]) = va;
    *reinterpret_cast<s16x8*>(&T[sr][lo + 8]) = vb;
    __syncthreads();
    const int lr = t >> 2;
    const int sof = (t & 3) * 16;
    s16x8 wa, wb;
    #pragma unroll
    for (int j = 0; j < 8; ++j) {
        wa[j] = (short)T[sof + j][lr];
        wb[j] = (short)T[sof + 8 + j][lr];
    }
    u16* op = CmT + ((size_t)(b * LSEQ + l0 + lr)) * SDIM + sof;
    *reinterpret_cast<s16x8*>(op + 0) = wa;
    *reinterpret_cast<s16x8*>(op + 8) = wb;
}

// ---------------- k23: fused dwconv(B,dt) + softmax + AB (bf16 out) ----------------
__global__ __launch_bounds__(256) void k23_ab(const u16* __restrict__ rawbc,
                                              const float* __restrict__ rawdt,
                                              const float* __restrict__ Wdw,
                                              const float* __restrict__ Ap,
                                              u16* __restrict__ AB) {
    __shared__ float chB[LSEQ];
    __shared__ float chT[LSEQ];
    __shared__ float red[4];
    const int t = threadIdx.x;
    const int s = blockIdx.x;
    const int b = blockIdx.y;
    const u16* rB = rawbc + ((size_t)b * 128 + s) * LSEQ;
    const float* rT = rawdt + ((size_t)b * 64 + s) * LSEQ;
    #pragma unroll
    for (int i = 0; i < 16; ++i) {
        int idx = t + i * 256;
        chB[idx] = b2f(rB[idx]);
        chT[idx] = rT[idx];
    }
    __syncthreads();
    float wB[9], wT[9];
    #pragma unroll
    for (int k = 0; k < 9; ++k) {
        wB[k] = Wdw[s * 9 + k];
        wT[k] = Wdw[(128 + s) * 9 + k];
    }
    const float a = Ap[s];
    float vB[16], vT[16];
    float m = -3.0e38f;
    #pragma unroll
    for (int i = 0; i < 16; ++i) {
        int idx = t + i * 256;
        int row = idx >> 6, col = idx & 63;
        float aB = 0.f, aT = 0.f;
        #pragma unroll
        for (int dy = -1; dy <= 1; ++dy) {
            int r = row + dy;
            if (r < 0 || r > 63) continue;
            #pragma unroll
            for (int dx = -1; dx <= 1; ++dx) {
                int cc = col + dx;
                if (cc < 0 || cc > 63) continue;
                int p = r * 64 + cc;
                int wi = (dy + 1) * 3 + (dx + 1);
                aB = fmaf(wB[wi], chB[p], aB);
                aT = fmaf(wT[wi], chT[p], aT);
            }
        }
        vB[i] = aB;
        vT[i] = aT + a;
        m = fmaxf(m, vT[i]);
    }
    #pragma unroll
    for (int off = 32; off; off >>= 1) m = fmaxf(m, __shfl_xor(m, off));
    if ((t & 63) == 0) red[t >> 6] = m;
    __syncthreads();
    m = fmaxf(fmaxf(red[0], red[1]), fmaxf(red[2], red[3]));
    __syncthreads();
    float sum = 0.f;
    #pragma unroll
    for (int i = 0; i < 16; ++i) {
        vT[i] = expf(vT[i] - m);
        sum += vT[i];
    }
    #pragma unroll
    for (int off = 32; off; off >>= 1) sum += __shfl_xor(sum, off);
    if ((t & 63) == 0) red[t >> 6] = sum;
    __syncthreads();
    sum = red[0] + red[1] + red[2] + red[3];
    const float inv = 1.0f / sum;
    u16* op = AB + ((size_t)b * SDIM + s) * LSEQ;
    #pragma unroll
    for (int i = 0; i < 16; ++i) {
        int idx = t + i * 256;
        op[idx] = f2b(vT[i] * inv * vB[i]);
    }
}

// ---------------- k4: hpartT[kc][b*64+s][d] = x_chunk AB_chunk^T (MFMA) ------------
// grid (6 dtiles, 8 kchunks, 16 b); K-chunk 512
__global__ __launch_bounds__(256) void k4_mfma(const float* __restrict__ x,
                                               const u16* __restrict__ ABu,
                                               float* __restrict__ hpart) {
    __shared__ __align__(16) short As[64 * 40];
    __shared__ __align__(16) short Bs[64 * 40];
    const int t = threadIdx.x;
    const int d0 = blockIdx.x * 64;
    const int kc = blockIdx.y;
    const int b = blockIdx.z;
    const int lane = t & 63;
    const int w = t >> 6;
    const int wm = w >> 1, wn = w & 1;
    const int lm = lane & 15, kg = lane >> 4;
    const int arow = t >> 2;
    const int aoff = (t & 3) * 8;
    const float* ap = x + ((size_t)(b * DMODEL + d0 + arow)) * LSEQ + kc * 512 + aoff;
    const u16* bp = ABu + ((size_t)(b * SDIM + arow)) * LSEQ + kc * 512 + aoff;
    f32x4 acc[2][2];
    #pragma unroll
    for (int i = 0; i < 2; ++i)
        #pragma unroll
        for (int j = 0; j < 2; ++j) acc[i][j] = (f32x4){0.f, 0.f, 0.f, 0.f};

    for (int ks = 0; ks < 512; ks += 32) {
        float4 a0 = *reinterpret_cast<const float4*>(ap + ks);
        float4 a1 = *reinterpret_cast<const float4*>(ap + ks + 4);
        s16x8 av;
        av[0] = (short)f2b(a0.x); av[1] = (short)f2b(a0.y); av[2] = (short)f2b(a0.z); av[3] = (short)f2b(a0.w);
        av[4] = (short)f2b(a1.x); av[5] = (short)f2b(a1.y); av[6] = (short)f2b(a1.z); av[7] = (short)f2b(a1.w);
        s16x8 bv = *reinterpret_cast<const s16x8*>(bp + ks);
        *reinterpret_cast<s16x8*>(&As[arow * 40 + aoff]) = av;
        *reinterpret_cast<s16x8*>(&Bs[arow * 40 + aoff]) = bv;
        __syncthreads();
        s16x8 af[2], bf[2];
        #pragma unroll
        for (int i = 0; i < 2; ++i) {
            af[i] = *reinterpret_cast<s16x8*>(&As[(wm * 32 + i * 16 + lm) * 40 + kg * 8]);
            bf[i] = *reinterpret_cast<s16x8*>(&Bs[(wn * 32 + i * 16 + lm) * 40 + kg * 8]);
        }
        #pragma unroll
        for (int i = 0; i < 2; ++i)
            #pragma unroll
            for (int j = 0; j < 2; ++j)
                acc[i][j] = __builtin_amdgcn_mfma_f32_16x16x32_bf16(af[i], bf[j], acc[i][j], 0, 0, 0);
        __syncthreads();
    }
    #pragma unroll
    for (int i = 0; i < 2; ++i) {
        #pragma unroll
        for (int j = 0; j < 2; ++j) {
            int d = d0 + wm * 32 + i * 16 + kg * 4;
            int s = wn * 32 + j * 16 + lm;
            float* p = hpart + (size_t)kc * (1024 * DMODEL) + ((size_t)b * 64 + s) * DMODEL + d;
            *reinterpret_cast<f32x4*>(p) = acc[i][j];
        }
    }
}

// ---------------- k4r: HTB[bs][d] = bf16(sum of 8 hpartT) ----------------
__global__ __launch_bounds__(256) void k4r(const float* __restrict__ hp,
                                           u16* __restrict__ htb) {
    const int i = (blockIdx.x * 256 + threadIdx.x) * 4;   // grid 384 covers 393216*4
    const int N = 1024 * DMODEL;
    float sx = 0.f, sy = 0.f, sz = 0.f, sw = 0.f;
    #pragma unroll
    for (int kc = 0; kc < 8; ++kc) {
        float4 v = *reinterpret_cast<const float4*>(hp + (size_t)kc * N + i);
        sx += v.x; sy += v.y; sz += v.z; sw += v.w;
    }
    ushort4 o;
    o.x = f2b(sx); o.y = f2b(sy); o.z = f2b(sz); o.w = f2b(sw);
    *reinterpret_cast<ushort4*>(htb + i) = o;
}

// ---------------- k5hz: HZT[bs][o] = HTB[bs][:] . Whz[o][:] (MFMA) ----------------
__global__ __launch_bounds__(256) void k5hz(const u16* __restrict__ HTB,
                                            const float* __restrict__ Whz,
                                            float* __restrict__ HZT) {
    __shared__ __align__(16) short As[64 * 40];
    __shared__ __align__(16) short Bs[64 * 40];
    const int t = threadIdx.x;
    const int m0 = blockIdx.x * 64;
    const int n0 = blockIdx.y * 64;
    const int lane = t & 63;
    const int w = t >> 6;
    const int wm = w >> 1, wn = w & 1;
    const int lm = lane & 15, kg = lane >> 4;
    const int arow = t >> 2;
    const int aoff = (t & 3) * 8;
    const u16* apg = HTB + (size_t)(m0 + arow) * DMODEL + aoff;
    const float* bpg = Whz + (size_t)(n0 + arow) * DMODEL + aoff;
    f32x4 acc[2][2];
    #pragma unroll
    for (int i = 0; i < 2; ++i)
        #pragma unroll
        for (int j = 0; j < 2; ++j) acc[i][j] = (f32x4){0.f, 0.f, 0.f, 0.f};

    for (int kc = 0; kc < DMODEL; kc += 32) {
        s16x8 av = *reinterpret_cast<const s16x8*>(apg + kc);
        float4 b0 = *reinterpret_cast<const float4*>(bpg + kc);
        float4 b1 = *reinterpret_cast<const float4*>(bpg + kc + 4);
        s16x8 bv;
        bv[0] = (short)f2b(b0.x); bv[1] = (short)f2b(b0.y); bv[2] = (short)f2b(b0.z); bv[3] = (short)f2b(b0.w);
        bv[4] = (short)f2b(b1.x); bv[5] = (short)f2b(b1.y); bv[6] = (short)f2b(b1.z); bv[7] = (short)f2b(b1.w);
        *reinterpret_cast<s16x8*>(&As[arow * 40 + aoff]) = av;
        *reinterpret_cast<s16x8*>(&Bs[arow * 40 + aoff]) = bv;
        __syncthreads();
        s16x8 af[2], bf[2];
        #pragma unroll
        for (int i = 0; i < 2; ++i) {
            af[i] = *reinterpret_cast<s16x8*>(&As[(wm * 32 + i * 16 + lm) * 40 + kg * 8]);
            bf[i] = *reinterpret_cast<s16x8*>(&Bs[(wn * 32 + i * 16 + lm) * 40 + kg * 8]);
        }
        #pragma unroll
        for (int i = 0; i < 2; ++i)
            #pragma unroll
            for (int j = 0; j < 2; ++j)
                acc[i][j] = __builtin_amdgcn_mfma_f32_16x16x32_bf16(af[i], bf[j], acc[i][j], 0, 0, 0);
        __syncthreads();
    }
    #pragma unroll
    for (int i = 0; i < 2; ++i) {
        #pragma unroll
        for (int j = 0; j < 2; ++j) {
            #pragma unroll
            for (int r = 0; r < 4; ++r) {
                int bs = m0 + wm * 32 + i * 16 + kg * 4 + r;
                int o = n0 + wn * 32 + j * 16 + lm;
                HZT[(size_t)bs * 768 + o] = acc[i][j][r];
            }
        }
    }
}

// ---------------- k5g: HGT[bs][d] = bf16(h1 * (silu(z) + D)) ----------------
__global__ __launch_bounds__(256) void k5g(const float* __restrict__ HZT,
                                           const float* __restrict__ Dp,
                                           u16* __restrict__ HGT) {
    const int i = (blockIdx.x * 256 + threadIdx.x) * 4;   // grid 384 covers 1024*384
    const int bs = i / DMODEL, d = i - bs * DMODEL;
    const float* p = HZT + (size_t)bs * 768 + d;
    float4 h1 = *reinterpret_cast<const float4*>(p);
    float4 z  = *reinterpret_cast<const float4*>(p + DMODEL);
    const float Dv = Dp[0];
    ushort4 o;
    o.x = f2b(h1.x * (z.x / (1.f + expf(-z.x)) + Dv));
    o.y = f2b(h1.y * (z.y / (1.f + expf(-z.y)) + Dv));
    o.z = f2b(h1.z * (z.z / (1.f + expf(-z.z)) + Dv));
    o.w = f2b(h1.w * (z.w / (1.f + expf(-z.w)) + Dv));
    *reinterpret_cast<ushort4*>(HGT + i) = o;
}

// ---------------- k5ho: hout = HGT . Wout^T (MFMA); writes ho f32 + hob bf16 -------
__global__ __launch_bounds__(256) void k5ho(const u16* __restrict__ HGT,
                                            const float* __restrict__ Wout,
                                            float* __restrict__ ho,
                                            u16* __restrict__ hob) {
    __shared__ __align__(16) short As[64 * 40];
    __shared__ __align__(16) short Bs[64 * 40];
    const int t = threadIdx.x;
    const int m0 = blockIdx.x * 64;
    const int n0 = blockIdx.y * 64;
    const int lane = t & 63;
    const int w = t >> 6;
    const int wm = w >> 1, wn = w & 1;
    const int lm = lane & 15, kg = lane >> 4;
    const int arow = t >> 2;
    const int aoff = (t & 3) * 8;
    const u16* apg = HGT + (size_t)(m0 + arow) * DMODEL + aoff;
    const float* bpg = Wout + (size_t)(n0 + arow) * DMODEL + aoff;
    f32x4 acc[2][2];
    #pragma unroll
    for (int i = 0; i < 2; ++i)
        #pragma unroll
        for (int j = 0; j < 2; ++j) acc[i][j] = (f32x4){0.f, 0.f, 0.f, 0.f};

    for (int kc = 0; kc < DMODEL; kc += 32) {
        s16x8 av = *reinterpret_cast<const s16x8*>(apg + kc);
        float4 b0 = *reinterpret_cast<const float4*>(bpg + kc);
        float4 b1 = *reinterpret_cast<const float4*>(bpg + kc + 4);
        s16x8 bv;
        bv[0] = (short)f2b(b0.x); bv[1] = (short)f2b(b0.y); bv[2] = (short)f2b(b0.z); bv[3] = (short)f2b(b0.w);
        bv[4] = (short)f2b(b1.x); bv[5] = (short)f2b(b1.y); bv[6] = (short)f2b(b1.z); bv[7] = (short)f2b(b1.w);
        *reinterpret_cast<s16x8*>(&As[arow * 40 + aoff]) = av;
        *reinterpret_cast<s16x8*>(&Bs[arow * 40 + aoff]) = bv;
        __syncthreads();
        s16x8 af[2], bf[2];
        #pragma unroll
        for (int i = 0; i < 2; ++i) {
            af[i] = *reinterpret_cast<s16x8*>(&As[(wm * 32 + i * 16 + lm) * 40 + kg * 8]);
            bf[i] = *reinterpret_cast<s16x8*>(&Bs[(wn * 32 + i * 16 + lm) * 40 + kg * 8]);
        }
        #pragma unroll
        for (int i = 0; i < 2; ++i)
            #pragma unroll
            for (int j = 0; j < 2; ++j)
                acc[i][j] = __builtin_amdgcn_mfma_f32_16x16x32_bf16(af[i], bf[j], acc[i][j], 0, 0, 0);
        __syncthreads();
    }
    #pragma unroll
    for (int i = 0; i < 2; ++i) {
        #pragma unroll
        for (int j = 0; j < 2; ++j) {
            int bs = m0 + wm * 32 + i * 16 + kg * 4;
            int b = bs >> 6, s = bs & 63;
            int o = n0 + wn * 32 + j * 16 + lm;
            size_t idx = ((size_t)b * DMODEL + o) * SDIM + s;
            *reinterpret_cast<f32x4*>(ho + idx) = acc[i][j];
            ushort4 u;
            u.x = f2b(acc[i][j][0]); u.y = f2b(acc[i][j][1]);
            u.z = f2b(acc[i][j][2]); u.w = f2b(acc[i][j][3]);
            *reinterpret_cast<ushort4*>(hob + idx) = u;
        }
    }
}

// ---------------- k6: y = hob x CmT (MFMA, no LDS) ----------------
__global__ __launch_bounds__(256) void k6_mfma(const u16* __restrict__ CmT,
                                               const u16* __restrict__ hob,
                                               float* __restrict__ y) {
    const int t = threadIdx.x;
    const int l0 = blockIdx.x * 128;
    const int d0 = blockIdx.y * 128;
    const int b = blockIdx.z;
    const int lane = t & 63;
    const int w = t >> 6;
    const int wm = w >> 1, wn = w & 1;
    const int lm = lane & 15, kg = lane >> 4;
    const u16* hp = hob + (size_t)b * DMODEL * SDIM;
    const u16* cp = CmT + (size_t)b * LSEQ * SDIM;
    s16x8 af[4][2], bf[4][2];
    #pragma unroll
    for (int i = 0; i < 4; ++i)
        #pragma unroll
        for (int ks = 0; ks < 2; ++ks)
            af[i][ks] = *reinterpret_cast<const s16x8*>(
                hp + (size_t)(d0 + wm * 64 + i * 16 + lm) * SDIM + ks * 32 + kg * 8);
    #pragma unroll
    for (int j = 0; j < 4; ++j)
        #pragma unroll
        for (int ks = 0; ks < 2; ++ks)
            bf[j][ks] = *reinterpret_cast<const s16x8*>(
                cp + (size_t)(l0 + wn * 64 + j * 16 + lm) * SDIM + ks * 32 + kg * 8);
    f32x4 acc[4][4];
    #pragma unroll
    for (int i = 0; i < 4; ++i)
        #pragma unroll
        for (int j = 0; j < 4; ++j) acc[i][j] = (f32x4){0.f, 0.f, 0.f, 0.f};
    #pragma unroll
    for (int ks = 0; ks < 2; ++ks)
        #pragma unroll
        for (int i = 0; i < 4; ++i)
            #pragma unroll
            for (int j = 0; j < 4; ++j)
                acc[i][j] = __builtin_amdgcn_mfma_f32_16x16x32_bf16(af[i][ks], bf[j][ks], acc[i][j], 0, 0, 0);
    float* yp = y + (size_t)b * DMODEL * LSEQ;
    #pragma unroll
    for (int i = 0; i < 4; ++i) {
        #pragma unroll
        for (int j = 0; j < 4; ++j) {
            #pragma unroll
            for (int r = 0; r < 4; ++r) {
                int d = d0 + wm * 64 + i * 16 + kg * 4 + r;
                int l = l0 + wn * 64 + j * 16 + lm;
                yp[(size_t)d * LSEQ + l] = acc[i][j][r];
            }
        }
    }
}

extern "C" void kernel_launch(void* const* d_in, const int* in_sizes, int n_in,
                              void* d_out, int out_size, void* d_ws, size_t ws_size,
                              hipStream_t stream) {
    const float* x    = (const float*)d_in[0];
    const float* Wb   = (const float*)d_in[1];
    const float* Wdw  = (const float*)d_in[2];
    const float* Whz  = (const float*)d_in[3];
    const float* Wout = (const float*)d_in[4];
    const float* Ap   = (const float*)d_in[5];
    const float* Dp   = (const float*)d_in[6];

    float* out = (float*)d_out;
    const size_t YSIZE = (size_t)NB * DMODEL * LSEQ;   // 25165824 floats

    // d_out y-region scratch (float offsets), all dead before k6 rewrites y:
    //   RAWBC (u16) [0,        4194304)   bcdt ch 0..127 bf16 (dead after k23)
    //   RAWDT (f32) [4194304,  8388608)   bcdt ch 128..191 f32 (dead after k23)
    //   XBT   (u16) [8388608,  20971520)  bf16 x^T (dead after k1)
    //     CMB (u16) [8388608, 10485760)   bf16 Cm (after k1; dead after kcmT)
    //   AB    (u16) [20971520, 23068672)  bf16 AB (dead after k4)
    //   Phase2+ (reusing dead RAWBC/RAWDT region, all after k23):
    //   HPART f32 [0, 3145728)        8 x [1024][384]  (h^T partials)
    //   HTB   u16 [3145728, 3342336)  [1024][384] bf16 h^T
    //   HZT   f32 [3342336, 4128768)  [1024][768]
    //   HGT   u16 [4128768, 4325376)  [1024][384] bf16
    // ws: CmT u16 [0, 4194304), HOB u16 [4194304, 4587520)
    u16*   RAWBC  = (u16*)out;
    float* RAWDT  = out + 4194304;
    u16*   XBT    = (u16*)(out + 8388608);
    u16*   CMB    = (u16*)(out + 8388608);
    u16*   ABu    = (u16*)(out + 20971520);
    float* HPART  = out;
    u16*   HTB    = (u16*)(out + 3145728);
    float* HZT    = out + 3342336;
    u16*   HGT    = (u16*)(out + 4128768);
    float* HO     = out + YSIZE;       // hout output (f32)
    u16*   CmT    = (u16*)d_ws;
    u16*   HOB    = (u16*)d_ws + 4194304;

    kcvt   <<<dim3(64, 6, NB), 256, 0, stream>>>(x, XBT);
    k1_mfma<<<dim3(16, NB), 512, 0, stream>>>(XBT, Wb, RAWBC, RAWDT);
    k2c_cm <<<dim3(16, SDIM, NB), 256, 0, stream>>>(RAWBC, Wdw, CMB);
    kcmT   <<<dim3(64, NB), 256, 0, stream>>>(CMB, CmT);
    k23_ab <<<dim3(SDIM, NB), 256, 0, stream>>>(RAWBC, RAWDT, Wdw, Ap, ABu);
    k4_mfma<<<dim3(6, 8, NB), 256, 0, stream>>>(x, ABu, HPART);
    k4r    <<<dim3(384), 256, 0, stream>>>(HPART, HTB);
    k5hz   <<<dim3(16, 12), 256, 0, stream>>>(HTB, Whz, HZT);
    k5g    <<<dim3(384), 256, 0, stream>>>(HZT, Dp, HGT);
    k5ho   <<<dim3(16, 6), 256, 0, stream>>>(HGT, Wout, HO, HOB);
    k6_mfma<<<dim3(32, 3, NB), 256, 0, stream>>>(CmT, HOB, out);
}

// Round 10
// 149.484 us; speedup vs baseline: 1.1783x; 1.1783x over previous
//
#include <hip/hip_runtime.h>

typedef unsigned short u16;
typedef short s16x8 __attribute__((ext_vector_type(8)));
typedef float f32x4 __attribute__((ext_vector_type(4)));

#define NB 16
#define DMODEL 384
#define SDIM 64
#define LSEQ 4096
#define C3S 192

__device__ __forceinline__ float b2f(u16 u) {
    union { unsigned int i; float f; } v; v.i = ((unsigned int)u) << 16; return v.f;
}
__device__ __forceinline__ u16 f2b(float f) {
    union { float ff; unsigned int i; } v; v.ff = f;
    unsigned int x = v.i;
    unsigned int r = (x + 0x7fffu + ((x >> 16) & 1u)) >> 16;
    return (u16)r;
}

// ---------------- kcvt: xbT[b,l,d] = bf16(x^T) ----------------
__global__ __launch_bounds__(256) void kcvt(const float* __restrict__ x,
                                            u16* __restrict__ xbT) {
    __shared__ __align__(16) u16 T[64][72];
    const int t = threadIdx.x;
    const int l0 = blockIdx.x * 64;
    const int d0 = blockIdx.y * 64;
    const int b = blockIdx.z;
    const int dr = t >> 2;
    const int lo = (t & 3) * 16;
    const float* xp = x + ((size_t)(b * DMODEL + d0 + dr)) * LSEQ + l0 + lo;
    float4 x0 = *reinterpret_cast<const float4*>(xp + 0);
    float4 x1 = *reinterpret_cast<const float4*>(xp + 4);
    float4 x2 = *reinterpret_cast<const float4*>(xp + 8);
    float4 x3 = *reinterpret_cast<const float4*>(xp + 12);
    s16x8 va, vb;
    va[0] = (short)f2b(x0.x); va[1] = (short)f2b(x0.y); va[2] = (short)f2b(x0.z); va[3] = (short)f2b(x0.w);
    va[4] = (short)f2b(x1.x); va[5] = (short)f2b(x1.y); va[6] = (short)f2b(x1.z); va[7] = (short)f2b(x1.w);
    vb[0] = (short)f2b(x2.x); vb[1] = (short)f2b(x2.y); vb[2] = (short)f2b(x2.z); vb[3] = (short)f2b(x2.w);
    vb[4] = (short)f2b(x3.x); vb[5] = (short)f2b(x3.y); vb[6] = (short)f2b(x3.z); vb[7] = (short)f2b(x3.w);
    *reinterpret_cast<s16x8*>(&T[dr][lo + 0]) = va;
    *reinterpret_cast<s16x8*>(&T[dr][lo + 8]) = vb;
    __syncthreads();
    const int lr = t >> 2;
    const int dof = (t & 3) * 16;
    s16x8 wa, wb;
    #pragma unroll
    for (int j = 0; j < 8; ++j) {
        wa[j] = (short)T[dof + j][lr];
        wb[j] = (short)T[dof + 8 + j][lr];
    }
    u16* xtp = xbT + ((size_t)(b * LSEQ + l0 + lr)) * DMODEL + d0 + dof;
    *reinterpret_cast<s16x8*>(xtp + 0) = wa;
    *reinterpret_cast<s16x8*>(xtp + 8) = wb;
}

// ---------------- k1: rawb[b,o,l] = bf16(W_bcdt x) for all 192 o (MFMA) ------------
// grid (16 ltiles of 256, 3 otiles of 64, 16 b), block 256 (4 waves, 2x2)
__global__ __launch_bounds__(256) void k1_mfma(const u16* __restrict__ xbT,
                                               const float* __restrict__ Wb,
                                               u16* __restrict__ rawb) {
    __shared__ __align__(16) short As[64 * 40];
    __shared__ __align__(16) short Bs[256 * 40];
    const int t = threadIdx.x;
    const int l0 = blockIdx.x * 256;
    const int o0 = blockIdx.y * 64;
    const int b = blockIdx.z;
    const int lane = t & 63;
    const int w = t >> 6;
    const int wm = w >> 1, wn = w & 1;
    const int lm = lane & 15, kg = lane >> 4;
    f32x4 acc[2][8];
    #pragma unroll
    for (int i = 0; i < 2; ++i)
        #pragma unroll
        for (int j = 0; j < 8; ++j) acc[i][j] = (f32x4){0.f, 0.f, 0.f, 0.f};

    const int arow = t >> 2;
    const int aoff = (t & 3) * 8;
    const float* wp = Wb + (size_t)(o0 + arow) * DMODEL + aoff;
    const u16* bp = xbT + ((size_t)(b * LSEQ + l0)) * DMODEL;

    for (int kc = 0; kc < DMODEL; kc += 32) {
        float4 w0 = *reinterpret_cast<const float4*>(wp + kc);
        float4 w1 = *reinterpret_cast<const float4*>(wp + kc + 4);
        s16x8 av;
        av[0] = (short)f2b(w0.x); av[1] = (short)f2b(w0.y); av[2] = (short)f2b(w0.z); av[3] = (short)f2b(w0.w);
        av[4] = (short)f2b(w1.x); av[5] = (short)f2b(w1.y); av[6] = (short)f2b(w1.z); av[7] = (short)f2b(w1.w);
        *reinterpret_cast<s16x8*>(&As[arow * 40 + aoff]) = av;
        #pragma unroll
        for (int i = 0; i < 4; ++i) {
            int c = t + i * 256;
            int brow = c >> 2;
            int boff = (c & 3) * 8;
            s16x8 bv = *reinterpret_cast<const s16x8*>(bp + (size_t)brow * DMODEL + kc + boff);
            *reinterpret_cast<s16x8*>(&Bs[brow * 40 + boff]) = bv;
        }
        __syncthreads();
        s16x8 af[2], bf[8];
        #pragma unroll
        for (int i = 0; i < 2; ++i)
            af[i] = *reinterpret_cast<s16x8*>(&As[(wm * 32 + i * 16 + lm) * 40 + kg * 8]);
        #pragma unroll
        for (int j = 0; j < 8; ++j)
            bf[j] = *reinterpret_cast<s16x8*>(&Bs[(wn * 128 + j * 16 + lm) * 40 + kg * 8]);
        #pragma unroll
        for (int i = 0; i < 2; ++i)
            #pragma unroll
            for (int j = 0; j < 8; ++j)
                acc[i][j] = __builtin_amdgcn_mfma_f32_16x16x32_bf16(af[i], bf[j], acc[i][j], 0, 0, 0);
        __syncthreads();
    }
    #pragma unroll
    for (int i = 0; i < 2; ++i) {
        #pragma unroll
        for (int j = 0; j < 8; ++j) {
            #pragma unroll
            for (int r = 0; r < 4; ++r) {
                int o = o0 + wm * 32 + i * 16 + kg * 4 + r;
                int l = l0 + wn * 128 + j * 16 + lm;
                rawb[((size_t)b * C3S + o) * LSEQ + l] = f2b(acc[i][j][r]);
            }
        }
    }
}

// ---------------- k23: fused 3x dwconv + softmax; writes AB and CMB (bf16) ---------
// grid (64 s, 16 b), block 256, 16 pixels/thread; B,C,dt channels staged bf16 in LDS
__global__ __launch_bounds__(256) void k23_ab(const u16* __restrict__ rawb,
                                              const float* __restrict__ Wdw,
                                              const float* __restrict__ Ap,
                                              u16* __restrict__ AB,
                                              u16* __restrict__ CMB) {
    __shared__ __align__(16) u16 chB[LSEQ];
    __shared__ __align__(16) u16 chC[LSEQ];
    __shared__ __align__(16) u16 chT[LSEQ];
    __shared__ float red[4];
    const int t = threadIdx.x;
    const int s = blockIdx.x;
    const int b = blockIdx.y;
    const u16* rB = rawb + ((size_t)b * C3S + s) * LSEQ;
    const u16* rC = rawb + ((size_t)b * C3S + 64 + s) * LSEQ;
    const u16* rT = rawb + ((size_t)b * C3S + 128 + s) * LSEQ;
    #pragma unroll
    for (int i = 0; i < 2; ++i) {
        int c8 = (t + i * 256) * 8;
        *reinterpret_cast<s16x8*>(&chB[c8]) = *reinterpret_cast<const s16x8*>(rB + c8);
        *reinterpret_cast<s16x8*>(&chC[c8]) = *reinterpret_cast<const s16x8*>(rC + c8);
        *reinterpret_cast<s16x8*>(&chT[c8]) = *reinterpret_cast<const s16x8*>(rT + c8);
    }
    __syncthreads();
    float wB[9], wC[9], wT[9];
    #pragma unroll
    for (int k = 0; k < 9; ++k) {
        wB[k] = Wdw[s * 9 + k];
        wC[k] = Wdw[(64 + s) * 9 + k];
        wT[k] = Wdw[(128 + s) * 9 + k];
    }
    const float a = Ap[s];
    u16* cmp = CMB + ((size_t)b * SDIM + s) * LSEQ;
    float vB[16], vT[16];
    float m = -3.0e38f;
    #pragma unroll
    for (int i = 0; i < 16; ++i) {
        int idx = t + i * 256;
        int row = idx >> 6, col = idx & 63;
        float aB = 0.f, aC = 0.f, aT = 0.f;
        #pragma unroll
        for (int dy = -1; dy <= 1; ++dy) {
            int r = row + dy;
            if (r < 0 || r > 63) continue;
            #pragma unroll
            for (int dx = -1; dx <= 1; ++dx) {
                int cc = col + dx;
                if (cc < 0 || cc > 63) continue;
                int p = r * 64 + cc;
                int wi = (dy + 1) * 3 + (dx + 1);
                aB = fmaf(wB[wi], b2f(chB[p]), aB);
                aC = fmaf(wC[wi], b2f(chC[p]), aC);
                aT = fmaf(wT[wi], b2f(chT[p]), aT);
            }
        }
        cmp[idx] = f2b(aC);
        vB[i] = aB;
        vT[i] = aT + a;
        m = fmaxf(m, vT[i]);
    }
    #pragma unroll
    for (int off = 32; off; off >>= 1) m = fmaxf(m, __shfl_xor(m, off));
    if ((t & 63) == 0) red[t >> 6] = m;
    __syncthreads();
    m = fmaxf(fmaxf(red[0], red[1]), fmaxf(red[2], red[3]));
    __syncthreads();
    float sum = 0.f;
    #pragma unroll
    for (int i = 0; i < 16; ++i) {
        vT[i] = expf(vT[i] - m);
        sum += vT[i];
    }
    #pragma unroll
    for (int off = 32; off; off >>= 1) sum += __shfl_xor(sum, off);
    if ((t & 63) == 0) red[t >> 6] = sum;
    __syncthreads();
    sum = red[0] + red[1] + red[2] + red[3];
    const float inv = 1.0f / sum;
    u16* op = AB + ((size_t)b * SDIM + s) * LSEQ;
    #pragma unroll
    for (int i = 0; i < 16; ++i) {
        int idx = t + i * 256;
        op[idx] = f2b(vT[i] * inv * vB[i]);
    }
}

// ---------------- kcmT: CmT[b,l,s] = CMB^T (bf16) ----------------
__global__ __launch_bounds__(256) void kcmT(const u16* __restrict__ CMB,
                                            u16* __restrict__ CmT) {
    __shared__ __align__(16) u16 T[64][72];
    const int t = threadIdx.x;
    const int l0 = blockIdx.x * 64;
    const int b = blockIdx.y;
    const int sr = t >> 2;
    const int lo = (t & 3) * 16;
    const u16* ip = CMB + ((size_t)(b * SDIM + sr)) * LSEQ + l0 + lo;
    s16x8 va = *reinterpret_cast<const s16x8*>(ip);
    s16x8 vb = *reinterpret_cast<const s16x8*>(ip + 8);
    *reinterpret_cast<s16x8*>(&T[sr][lo + 0]) = va;
    *reinterpret_cast<s16x8*>(&T[sr][lo + 8]) = vb;
    __syncthreads();
    const int lr = t >> 2;
    const int sof = (t & 3) * 16;
    s16x8 wa, wb;
    #pragma unroll
    for (int j = 0; j < 8; ++j) {
        wa[j] = (short)T[sof + j][lr];
        wb[j] = (short)T[sof + 8 + j][lr];
    }
    u16* op = CmT + ((size_t)(b * LSEQ + l0 + lr)) * SDIM + sof;
    *reinterpret_cast<s16x8*>(op + 0) = wa;
    *reinterpret_cast<s16x8*>(op + 8) = wb;
}

// ---------------- k4: hpartT[kc][b*64+s][d] = x_chunk AB_chunk^T (MFMA) ------------
// grid (6 dtiles, 4 kchunks, 16 b); K-chunk 1024
__global__ __launch_bounds__(256) void k4_mfma(const float* __restrict__ x,
                                               const u16* __restrict__ ABu,
                                               float* __restrict__ hpart) {
    __shared__ __align__(16) short As[64 * 40];
    __shared__ __align__(16) short Bs[64 * 40];
    const int t = threadIdx.x;
    const int d0 = blockIdx.x * 64;
    const int kc = blockIdx.y;
    const int b = blockIdx.z;
    const int lane = t & 63;
    const int w = t >> 6;
    const int wm = w >> 1, wn = w & 1;
    const int lm = lane & 15, kg = lane >> 4;
    const int arow = t >> 2;
    const int aoff = (t & 3) * 8;
    const float* ap = x + ((size_t)(b * DMODEL + d0 + arow)) * LSEQ + kc * 1024 + aoff;
    const u16* bp = ABu + ((size_t)(b * SDIM + arow)) * LSEQ + kc * 1024 + aoff;
    f32x4 acc[2][2];
    #pragma unroll
    for (int i = 0; i < 2; ++i)
        #pragma unroll
        for (int j = 0; j < 2; ++j) acc[i][j] = (f32x4){0.f, 0.f, 0.f, 0.f};

    for (int ks = 0; ks < 1024; ks += 32) {
        float4 a0 = *reinterpret_cast<const float4*>(ap + ks);
        float4 a1 = *reinterpret_cast<const float4*>(ap + ks + 4);
        s16x8 av;
        av[0] = (short)f2b(a0.x); av[1] = (short)f2b(a0.y); av[2] = (short)f2b(a0.z); av[3] = (short)f2b(a0.w);
        av[4] = (short)f2b(a1.x); av[5] = (short)f2b(a1.y); av[6] = (short)f2b(a1.z); av[7] = (short)f2b(a1.w);
        s16x8 bv = *reinterpret_cast<const s16x8*>(bp + ks);
        *reinterpret_cast<s16x8*>(&As[arow * 40 + aoff]) = av;
        *reinterpret_cast<s16x8*>(&Bs[arow * 40 + aoff]) = bv;
        __syncthreads();
        s16x8 af[2], bf[2];
        #pragma unroll
        for (int i = 0; i < 2; ++i) {
            af[i] = *reinterpret_cast<s16x8*>(&As[(wm * 32 + i * 16 + lm) * 40 + kg * 8]);
            bf[i] = *reinterpret_cast<s16x8*>(&Bs[(wn * 32 + i * 16 + lm) * 40 + kg * 8]);
        }
        #pragma unroll
        for (int i = 0; i < 2; ++i)
            #pragma unroll
            for (int j = 0; j < 2; ++j)
                acc[i][j] = __builtin_amdgcn_mfma_f32_16x16x32_bf16(af[i], bf[j], acc[i][j], 0, 0, 0);
        __syncthreads();
    }
    #pragma unroll
    for (int i = 0; i < 2; ++i) {
        #pragma unroll
        for (int j = 0; j < 2; ++j) {
            int d = d0 + wm * 32 + i * 16 + kg * 4;
            int s = wn * 32 + j * 16 + lm;
            float* p = hpart + (size_t)kc * (1024 * DMODEL) + ((size_t)b * 64 + s) * DMODEL + d;
            *reinterpret_cast<f32x4*>(p) = acc[i][j];
        }
    }
}

// ---------------- k4r: HTB[bs][d] = bf16(sum of 4 hpartT) ----------------
__global__ __launch_bounds__(256) void k4r(const float* __restrict__ hp,
                                           u16* __restrict__ htb) {
    const int i = (blockIdx.x * 256 + threadIdx.x) * 4;
    const int N = 1024 * DMODEL;
    float4 v0 = *reinterpret_cast<const float4*>(hp + i);
    float4 v1 = *reinterpret_cast<const float4*>(hp + N + i);
    float4 v2 = *reinterpret_cast<const float4*>(hp + 2 * N + i);
    float4 v3 = *reinterpret_cast<const float4*>(hp + 3 * N + i);
    ushort4 o;
    o.x = f2b(v0.x + v1.x + v2.x + v3.x);
    o.y = f2b(v0.y + v1.y + v2.y + v3.y);
    o.z = f2b(v0.z + v1.z + v2.z + v3.z);
    o.w = f2b(v0.w + v1.w + v2.w + v3.w);
    *reinterpret_cast<ushort4*>(htb + i) = o;
}

// ---------------- k5hz: HZT[bs][o] = HTB[bs][:] . Whz[o][:] (MFMA) ----------------
__global__ __launch_bounds__(256) void k5hz(const u16* __restrict__ HTB,
                                            const float* __restrict__ Whz,
                                            float* __restrict__ HZT) {
    __shared__ __align__(16) short As[64 * 40];
    __shared__ __align__(16) short Bs[64 * 40];
    const int t = threadIdx.x;
    const int m0 = blockIdx.x * 64;
    const int n0 = blockIdx.y * 64;
    const int lane = t & 63;
    const int w = t >> 6;
    const int wm = w >> 1, wn = w & 1;
    const int lm = lane & 15, kg = lane >> 4;
    const int arow = t >> 2;
    const int aoff = (t & 3) * 8;
    const u16* apg = HTB + (size_t)(m0 + arow) * DMODEL + aoff;
    const float* bpg = Whz + (size_t)(n0 + arow) * DMODEL + aoff;
    f32x4 acc[2][2];
    #pragma unroll
    for (int i = 0; i < 2; ++i)
        #pragma unroll
        for (int j = 0; j < 2; ++j) acc[i][j] = (f32x4){0.f, 0.f, 0.f, 0.f};

    for (int kc = 0; kc < DMODEL; kc += 32) {
        s16x8 av = *reinterpret_cast<const s16x8*>(apg + kc);
        float4 b0 = *reinterpret_cast<const float4*>(bpg + kc);
        float4 b1 = *reinterpret_cast<const float4*>(bpg + kc + 4);
        s16x8 bv;
        bv[0] = (short)f2b(b0.x); bv[1] = (short)f2b(b0.y); bv[2] = (short)f2b(b0.z); bv[3] = (short)f2b(b0.w);
        bv[4] = (short)f2b(b1.x); bv[5] = (short)f2b(b1.y); bv[6] = (short)f2b(b1.z); bv[7] = (short)f2b(b1.w);
        *reinterpret_cast<s16x8*>(&As[arow * 40 + aoff]) = av;
        *reinterpret_cast<s16x8*>(&Bs[arow * 40 + aoff]) = bv;
        __syncthreads();
        s16x8 af[2], bf[2];
        #pragma unroll
        for (int i = 0; i < 2; ++i) {
            af[i] = *reinterpret_cast<s16x8*>(&As[(wm * 32 + i * 16 + lm) * 40 + kg * 8]);
            bf[i] = *reinterpret_cast<s16x8*>(&Bs[(wn * 32 + i * 16 + lm) * 40 + kg * 8]);
        }
        #pragma unroll
        for (int i = 0; i < 2; ++i)
            #pragma unroll
            for (int j = 0; j < 2; ++j)
                acc[i][j] = __builtin_amdgcn_mfma_f32_16x16x32_bf16(af[i], bf[j], acc[i][j], 0, 0, 0);
        __syncthreads();
    }
    #pragma unroll
    for (int i = 0; i < 2; ++i) {
        #pragma unroll
        for (int j = 0; j < 2; ++j) {
            #pragma unroll
            for (int r = 0; r < 4; ++r) {
                int bs = m0 + wm * 32 + i * 16 + kg * 4 + r;
                int o = n0 + wn * 32 + j * 16 + lm;
                HZT[(size_t)bs * 768 + o] = acc[i][j][r];
            }
        }
    }
}

// ---------------- k5g: HGT[bs][d] = bf16(h1 * (silu(z) + D)) ----------------
__global__ __launch_bounds__(256) void k5g(const float* __restrict__ HZT,
                                           const float* __restrict__ Dp,
                                           u16* __restrict__ HGT) {
    const int i = (blockIdx.x * 256 + threadIdx.x) * 4;
    const int bs = i / DMODEL, d = i - bs * DMODEL;
    const float* p = HZT + (size_t)bs * 768 + d;
    float4 h1 = *reinterpret_cast<const float4*>(p);
    float4 z  = *reinterpret_cast<const float4*>(p + DMODEL);
    const float Dv = Dp[0];
    ushort4 o;
    o.x = f2b(h1.x * (z.x / (1.f + expf(-z.x)) + Dv));
    o.y = f2b(h1.y * (z.y / (1.f + expf(-z.y)) + Dv));
    o.z = f2b(h1.z * (z.z / (1.f + expf(-z.z)) + Dv));
    o.w = f2b(h1.w * (z.w / (1.f + expf(-z.w)) + Dv));
    *reinterpret_cast<ushort4*>(HGT + i) = o;
}

// ---------------- k5ho: hout = HGT . Wout^T (MFMA); writes ho f32 + hob bf16 -------
__global__ __launch_bounds__(256) void k5ho(const u16* __restrict__ HGT,
                                            const float* __restrict__ Wout,
                                            float* __restrict__ ho,
                                            u16* __restrict__ hob) {
    __shared__ __align__(16) short As[64 * 40];
    __shared__ __align__(16) short Bs[64 * 40];
    const int t = threadIdx.x;
    const int m0 = blockIdx.x * 64;
    const int n0 = blockIdx.y * 64;
    const int lane = t & 63;
    const int w = t >> 6;
    const int wm = w >> 1, wn = w & 1;
    const int lm = lane & 15, kg = lane >> 4;
    const int arow = t >> 2;
    const int aoff = (t & 3) * 8;
    const u16* apg = HGT + (size_t)(m0 + arow) * DMODEL + aoff;
    const float* bpg = Wout + (size_t)(n0 + arow) * DMODEL + aoff;
    f32x4 acc[2][2];
    #pragma unroll
    for (int i = 0; i < 2; ++i)
        #pragma unroll
        for (int j = 0; j < 2; ++j) acc[i][j] = (f32x4){0.f, 0.f, 0.f, 0.f};

    for (int kc = 0; kc < DMODEL; kc += 32) {
        s16x8 av = *reinterpret_cast<const s16x8*>(apg + kc);
        float4 b0 = *reinterpret_cast<const float4*>(bpg + kc);
        float4 b1 = *reinterpret_cast<const float4*>(bpg + kc + 4);
        s16x8 bv;
        bv[0] = (short)f2b(b0.x); bv[1] = (short)f2b(b0.y); bv[2] = (short)f2b(b0.z); bv[3] = (short)f2b(b0.w);
        bv[4] = (short)f2b(b1.x); bv[5] = (short)f2b(b1.y); bv[6] = (short)f2b(b1.z); bv[7] = (short)f2b(b1.w);
        *reinterpret_cast<s16x8*>(&As[arow * 40 + aoff]) = av;
        *reinterpret_cast<s16x8*>(&Bs[arow * 40 + aoff]) = bv;
        __syncthreads();
        s16x8 af[2], bf[2];
        #pragma unroll
        for (int i = 0; i < 2; ++i) {
            af[i] = *reinterpret_cast<s16x8*>(&As[(wm * 32 + i * 16 + lm) * 40 + kg * 8]);
            bf[i] = *reinterpret_cast<s16x8*>(&Bs[(wn * 32 + i * 16 + lm) * 40 + kg * 8]);
        }
        #pragma unroll
        for (int i = 0; i < 2; ++i)
            #pragma unroll
            for (int j = 0; j < 2; ++j)
                acc[i][j] = __builtin_amdgcn_mfma_f32_16x16x32_bf16(af[i], bf[j], acc[i][j], 0, 0, 0);
        __syncthreads();
    }
    #pragma unroll
    for (int i = 0; i < 2; ++i) {
        #pragma unroll
        for (int j = 0; j < 2; ++j) {
            int bs = m0 + wm * 32 + i * 16 + kg * 4;
            int b = bs >> 6, s = bs & 63;
            int o = n0 + wn * 32 + j * 16 + lm;
            size_t idx = ((size_t)b * DMODEL + o) * SDIM + s;
            *reinterpret_cast<f32x4*>(ho + idx) = acc[i][j];
            ushort4 u;
            u.x = f2b(acc[i][j][0]); u.y = f2b(acc[i][j][1]);
            u.z = f2b(acc[i][j][2]); u.w = f2b(acc[i][j][3]);
            *reinterpret_cast<ushort4*>(hob + idx) = u;
        }
    }
}

// ---------------- k6: y = hob x CmT (MFMA, no LDS) ----------------
__global__ __launch_bounds__(256) void k6_mfma(const u16* __restrict__ CmT,
                                               const u16* __restrict__ hob,
                                               float* __restrict__ y) {
    const int t = threadIdx.x;
    const int l0 = blockIdx.x * 128;
    const int d0 = blockIdx.y * 128;
    const int b = blockIdx.z;
    const int lane = t & 63;
    const int w = t >> 6;
    const int wm = w >> 1, wn = w & 1;
    const int lm = lane & 15, kg = lane >> 4;
    const u16* hp = hob + (size_t)b * DMODEL * SDIM;
    const u16* cp = CmT + (size_t)b * LSEQ * SDIM;
    s16x8 af[4][2], bf[4][2];
    #pragma unroll
    for (int i = 0; i < 4; ++i)
        #pragma unroll
        for (int ks = 0; ks < 2; ++ks)
            af[i][ks] = *reinterpret_cast<const s16x8*>(
                hp + (size_t)(d0 + wm * 64 + i * 16 + lm) * SDIM + ks * 32 + kg * 8);
    #pragma unroll
    for (int j = 0; j < 4; ++j)
        #pragma unroll
        for (int ks = 0; ks < 2; ++ks)
            bf[j][ks] = *reinterpret_cast<const s16x8*>(
                cp + (size_t)(l0 + wn * 64 + j * 16 + lm) * SDIM + ks * 32 + kg * 8);
    f32x4 acc[4][4];
    #pragma unroll
    for (int i = 0; i < 4; ++i)
        #pragma unroll
        for (int j = 0; j < 4; ++j) acc[i][j] = (f32x4){0.f, 0.f, 0.f, 0.f};
    #pragma unroll
    for (int ks = 0; ks < 2; ++ks)
        #pragma unroll
        for (int i = 0; i < 4; ++i)
            #pragma unroll
            for (int j = 0; j < 4; ++j)
                acc[i][j] = __builtin_amdgcn_mfma_f32_16x16x32_bf16(af[i][ks], bf[j][ks], acc[i][j], 0, 0, 0);
    float* yp = y + (size_t)b * DMODEL * LSEQ;
    #pragma unroll
    for (int i = 0; i < 4; ++i) {
        #pragma unroll
        for (int j = 0; j < 4; ++j) {
            #pragma unroll
            for (int r = 0; r < 4; ++r) {
                int d = d0 + wm * 64 + i * 16 + kg * 4 + r;
                int l = l0 + wn * 64 + j * 16 + lm;
                yp[(size_t)d * LSEQ + l] = acc[i][j][r];
            }
        }
    }
}

extern "C" void kernel_launch(void* const* d_in, const int* in_sizes, int n_in,
                              void* d_out, int out_size, void* d_ws, size_t ws_size,
                              hipStream_t stream) {
    const float* x    = (const float*)d_in[0];
    const float* Wb   = (const float*)d_in[1];
    const float* Wdw  = (const float*)d_in[2];
    const float* Whz  = (const float*)d_in[3];
    const float* Wout = (const float*)d_in[4];
    const float* Ap   = (const float*)d_in[5];
    const float* Dp   = (const float*)d_in[6];

    float* out = (float*)d_out;
    const size_t YSIZE = (size_t)NB * DMODEL * LSEQ;   // 25165824 floats

    // d_out y-region scratch (float offsets), all dead before k6 rewrites y:
    //   RAWB (u16) [0,        6291456)   bcdt all 192 ch bf16 (dead after k23)
    //   XBT  (u16) [8388608,  20971520)  bf16 x^T (dead after k1)
    //     CMB (u16) [8388608, 10485760)  bf16 Cm (written by k23, after k1)
    //   AB   (u16) [20971520, 23068672)  bf16 AB (dead after k4)
    //   Phase2 (reusing dead RAWB region, all after k23):
    //   HPART f32 [0, 1572864)        4 x [1024][384]
    //   HTB   u16 [1572864, 1769472)  [1024][384] bf16
    //   HZT   f32 [1769472, 2555904)  [1024][768]
    //   HGT   u16 [2555904, 2752512)  [1024][384] bf16
    // ws: CmT u16 [0, 4194304), HOB u16 [4194304, 4587520)
    u16*   RAWB   = (u16*)out;
    u16*   XBT    = (u16*)(out + 8388608);
    u16*   CMB    = (u16*)(out + 8388608);
    u16*   ABu    = (u16*)(out + 20971520);
    float* HPART  = out;
    u16*   HTB    = (u16*)(out + 1572864);
    float* HZT    = out + 1769472;
    u16*   HGT    = (u16*)(out + 2555904);
    float* HO     = out + YSIZE;       // hout output (f32)
    u16*   CmT    = (u16*)d_ws;
    u16*   HOB    = (u16*)d_ws + 4194304;

    kcvt   <<<dim3(64, 6, NB), 256, 0, stream>>>(x, XBT);
    k1_mfma<<<dim3(16, 3, NB), 256, 0, stream>>>(XBT, Wb, RAWB);
    k23_ab <<<dim3(SDIM, NB), 256, 0, stream>>>(RAWB, Wdw, Ap, ABu, CMB);
    kcmT   <<<dim3(64, NB), 256, 0, stream>>>(CMB, CmT);
    k4_mfma<<<dim3(6, 4, NB), 256, 0, stream>>>(x, ABu, HPART);
    k4r    <<<dim3(384), 256, 0, stream>>>(HPART, HTB);
    k5hz   <<<dim3(16, 12), 256, 0, stream>>>(HTB, Whz, HZT);
    k5g    <<<dim3(384), 256, 0, stream>>>(HZT, Dp, HGT);
    k5ho   <<<dim3(16, 6), 256, 0, stream>>>(HGT, Wout, HO, HOB);
    k6_mfma<<<dim3(32, 3, NB), 256, 0, stream>>>(CmT, HOB, out);
}

// Round 11
// 141.663 us; speedup vs baseline: 1.2433x; 1.0552x over previous
//
#include <hip/hip_runtime.h>

typedef unsigned short u16;
typedef short s16x8 __attribute__((ext_vector_type(8)));
typedef float f32x4 __attribute__((ext_vector_type(4)));

#define NB 16
#define DMODEL 384
#define SDIM 64
#define LSEQ 4096
#define C3S 192

__device__ __forceinline__ float b2f(u16 u) {
    union { unsigned int i; float f; } v; v.i = ((unsigned int)u) << 16; return v.f;
}
__device__ __forceinline__ u16 f2b(float f) {
    union { float ff; unsigned int i; } v; v.ff = f;
    unsigned int x = v.i;
    unsigned int r = (x + 0x7fffu + ((x >> 16) & 1u)) >> 16;
    return (u16)r;
}

// ---------------- k01: fused x-transpose + bcdt GEMM (MFMA) ----------------
// rawb[b,o,l] = bf16( sum_d W[o,d] x[b,d,l] ), all 192 o per block.
// grid (32 ltiles of 128, 16 b), block 512 = 8 waves (4 o-waves x 2 l-waves).
// Per K-step (32 d): stage x rows into XR (bf16), rebuild k-major Bs via LDS
// transpose, stage W into As, then 12 MFMA per wave.
__global__ __launch_bounds__(512, 4) void k01_mfma(const float* __restrict__ x,
                                                   const float* __restrict__ Wb,
                                                   u16* __restrict__ rawb) {
    __shared__ __align__(16) u16  XR[32 * 136];    // [d-local][l-local], pad 136
    __shared__ __align__(16) short As[192 * 40];   // W bf16, k-major
    __shared__ __align__(16) short Bs[128 * 40];   // x^T bf16, k-major
    const int t = threadIdx.x;
    const int l0 = blockIdx.x * 128;
    const int b = blockIdx.y;
    const int lane = t & 63;
    const int w = t >> 6;
    const int wm = w >> 1, wn = w & 1;             // wm 0..3 (48 o), wn 0..1 (64 l)
    const int lm = lane & 15, kg = lane >> 4;

    f32x4 acc[3][4];
    #pragma unroll
    for (int i = 0; i < 3; ++i)
        #pragma unroll
        for (int j = 0; j < 4; ++j) acc[i][j] = (f32x4){0.f, 0.f, 0.f, 0.f};

    const int xr = t >> 4;            // 0..31 (d-local row)
    const int xli = (t & 15) * 8;     // l-local offset
    const int bl = t >> 2;            // 0..127 (l-local for Bs build)
    const int bdq = (t & 3) * 8;      // d-local offset for Bs build

    for (int kc = 0; kc < DMODEL; kc += 32) {
        // stage W rows (192 x 32) as bf16 k-major
        if (t < 192) {
            const float* wp = Wb + (size_t)t * DMODEL + kc;
            #pragma unroll
            for (int c = 0; c < 4; ++c) {
                float4 w0 = *reinterpret_cast<const float4*>(wp + c * 8);
                float4 w1 = *reinterpret_cast<const float4*>(wp + c * 8 + 4);
                s16x8 av;
                av[0] = (short)f2b(w0.x); av[1] = (short)f2b(w0.y); av[2] = (short)f2b(w0.z); av[3] = (short)f2b(w0.w);
                av[4] = (short)f2b(w1.x); av[5] = (short)f2b(w1.y); av[6] = (short)f2b(w1.z); av[7] = (short)f2b(w1.w);
                *reinterpret_cast<s16x8*>(&As[t * 40 + c * 8]) = av;
            }
        }
        // stage x rows (32 d x 128 l) as bf16, row-major
        {
            const float* xp = x + ((size_t)(b * DMODEL + kc + xr)) * LSEQ + l0 + xli;
            float4 x0 = *reinterpret_cast<const float4*>(xp);
            float4 x1 = *reinterpret_cast<const float4*>(xp + 4);
            s16x8 v;
            v[0] = (short)f2b(x0.x); v[1] = (short)f2b(x0.y); v[2] = (short)f2b(x0.z); v[3] = (short)f2b(x0.w);
            v[4] = (short)f2b(x1.x); v[5] = (short)f2b(x1.y); v[6] = (short)f2b(x1.z); v[7] = (short)f2b(x1.w);
            *reinterpret_cast<s16x8*>(&XR[xr * 136 + xli]) = v;
        }
        __syncthreads();
        // build Bs[l][d] (transpose read from XR)
        {
            s16x8 v;
            #pragma unroll
            for (int j = 0; j < 8; ++j) v[j] = (short)XR[(bdq + j) * 136 + bl];
            *reinterpret_cast<s16x8*>(&Bs[bl * 40 + bdq]) = v;
        }
        __syncthreads();
        s16x8 af[3], bf[4];
        #pragma unroll
        for (int i = 0; i < 3; ++i)
            af[i] = *reinterpret_cast<s16x8*>(&As[(wm * 48 + i * 16 + lm) * 40 + kg * 8]);
        #pragma unroll
        for (int j = 0; j < 4; ++j)
            bf[j] = *reinterpret_cast<s16x8*>(&Bs[(wn * 64 + j * 16 + lm) * 40 + kg * 8]);
        #pragma unroll
        for (int i = 0; i < 3; ++i)
            #pragma unroll
            for (int j = 0; j < 4; ++j)
                acc[i][j] = __builtin_amdgcn_mfma_f32_16x16x32_bf16(af[i], bf[j], acc[i][j], 0, 0, 0);
        __syncthreads();
    }
    #pragma unroll
    for (int i = 0; i < 3; ++i) {
        #pragma unroll
        for (int j = 0; j < 4; ++j) {
            #pragma unroll
            for (int r = 0; r < 4; ++r) {
                int o = wm * 48 + i * 16 + kg * 4 + r;
                int l = l0 + wn * 64 + j * 16 + lm;
                rawb[((size_t)b * C3S + o) * LSEQ + l] = f2b(acc[i][j][r]);
            }
        }
    }
}

// ---------------- k23: fused 3x dwconv + softmax; writes AB and CMB (bf16) ---------
__global__ __launch_bounds__(256) void k23_ab(const u16* __restrict__ rawb,
                                              const float* __restrict__ Wdw,
                                              const float* __restrict__ Ap,
                                              u16* __restrict__ AB,
                                              u16* __restrict__ CMB) {
    __shared__ __align__(16) u16 chB[LSEQ];
    __shared__ __align__(16) u16 chC[LSEQ];
    __shared__ __align__(16) u16 chT[LSEQ];
    __shared__ float red[4];
    const int t = threadIdx.x;
    const int s = blockIdx.x;
    const int b = blockIdx.y;
    const u16* rB = rawb + ((size_t)b * C3S + s) * LSEQ;
    const u16* rC = rawb + ((size_t)b * C3S + 64 + s) * LSEQ;
    const u16* rT = rawb + ((size_t)b * C3S + 128 + s) * LSEQ;
    #pragma unroll
    for (int i = 0; i < 2; ++i) {
        int c8 = (t + i * 256) * 8;
        *reinterpret_cast<s16x8*>(&chB[c8]) = *reinterpret_cast<const s16x8*>(rB + c8);
        *reinterpret_cast<s16x8*>(&chC[c8]) = *reinterpret_cast<const s16x8*>(rC + c8);
        *reinterpret_cast<s16x8*>(&chT[c8]) = *reinterpret_cast<const s16x8*>(rT + c8);
    }
    __syncthreads();
    float wB[9], wC[9], wT[9];
    #pragma unroll
    for (int k = 0; k < 9; ++k) {
        wB[k] = Wdw[s * 9 + k];
        wC[k] = Wdw[(64 + s) * 9 + k];
        wT[k] = Wdw[(128 + s) * 9 + k];
    }
    const float a = Ap[s];
    u16* cmp = CMB + ((size_t)b * SDIM + s) * LSEQ;
    float vB[16], vT[16];
    float m = -3.0e38f;
    #pragma unroll
    for (int i = 0; i < 16; ++i) {
        int idx = t + i * 256;
        int row = idx >> 6, col = idx & 63;
        float aB = 0.f, aC = 0.f, aT = 0.f;
        #pragma unroll
        for (int dy = -1; dy <= 1; ++dy) {
            int r = row + dy;
            if (r < 0 || r > 63) continue;
            #pragma unroll
            for (int dx = -1; dx <= 1; ++dx) {
                int cc = col + dx;
                if (cc < 0 || cc > 63) continue;
                int p = r * 64 + cc;
                int wi = (dy + 1) * 3 + (dx + 1);
                aB = fmaf(wB[wi], b2f(chB[p]), aB);
                aC = fmaf(wC[wi], b2f(chC[p]), aC);
                aT = fmaf(wT[wi], b2f(chT[p]), aT);
            }
        }
        cmp[idx] = f2b(aC);
        vB[i] = aB;
        vT[i] = aT + a;
        m = fmaxf(m, vT[i]);
    }
    #pragma unroll
    for (int off = 32; off; off >>= 1) m = fmaxf(m, __shfl_xor(m, off));
    if ((t & 63) == 0) red[t >> 6] = m;
    __syncthreads();
    m = fmaxf(fmaxf(red[0], red[1]), fmaxf(red[2], red[3]));
    __syncthreads();
    float sum = 0.f;
    #pragma unroll
    for (int i = 0; i < 16; ++i) {
        vT[i] = expf(vT[i] - m);
        sum += vT[i];
    }
    #pragma unroll
    for (int off = 32; off; off >>= 1) sum += __shfl_xor(sum, off);
    if ((t & 63) == 0) red[t >> 6] = sum;
    __syncthreads();
    sum = red[0] + red[1] + red[2] + red[3];
    const float inv = 1.0f / sum;
    u16* op = AB + ((size_t)b * SDIM + s) * LSEQ;
    #pragma unroll
    for (int i = 0; i < 16; ++i) {
        int idx = t + i * 256;
        op[idx] = f2b(vT[i] * inv * vB[i]);
    }
}

// ---------------- kcmT: CmT[b,l,s] = CMB^T (bf16) ----------------
__global__ __launch_bounds__(256) void kcmT(const u16* __restrict__ CMB,
                                            u16* __restrict__ CmT) {
    __shared__ __align__(16) u16 T[64][72];
    const int t = threadIdx.x;
    const int l0 = blockIdx.x * 64;
    const int b = blockIdx.y;
    const int sr = t >> 2;
    const int lo = (t & 3) * 16;
    const u16* ip = CMB + ((size_t)(b * SDIM + sr)) * LSEQ + l0 + lo;
    s16x8 va = *reinterpret_cast<const s16x8*>(ip);
    s16x8 vb = *reinterpret_cast<const s16x8*>(ip + 8);
    *reinterpret_cast<s16x8*>(&T[sr][lo + 0]) = va;
    *reinterpret_cast<s16x8*>(&T[sr][lo + 8]) = vb;
    __syncthreads();
    const int lr = t >> 2;
    const int sof = (t & 3) * 16;
    s16x8 wa, wb;
    #pragma unroll
    for (int j = 0; j < 8; ++j) {
        wa[j] = (short)T[sof + j][lr];
        wb[j] = (short)T[sof + 8 + j][lr];
    }
    u16* op = CmT + ((size_t)(b * LSEQ + l0 + lr)) * SDIM + sof;
    *reinterpret_cast<s16x8*>(op + 0) = wa;
    *reinterpret_cast<s16x8*>(op + 8) = wb;
}

// ---------------- k4: hpartT[kc][b*64+s][d] = x_chunk AB_chunk^T (MFMA) ------------
// grid (12 dtiles of 32, 4 kchunks, 16 b); K-chunk 1024
__global__ __launch_bounds__(256) void k4_mfma(const float* __restrict__ x,
                                               const u16* __restrict__ ABu,
                                               float* __restrict__ hpart) {
    __shared__ __align__(16) short As[32 * 40];
    __shared__ __align__(16) short Bs[64 * 40];
    const int t = threadIdx.x;
    const int d0 = blockIdx.x * 32;
    const int kc = blockIdx.y;
    const int b = blockIdx.z;
    const int lane = t & 63;
    const int w = t >> 6;
    const int wm = w >> 1, wn = w & 1;   // wm: d-half (16), wn: s-half (32)
    const int lm = lane & 15, kg = lane >> 4;
    const int arow = t >> 2;             // As: 0..31 (t<128); Bs: 0..63
    const int aoff = (t & 3) * 8;
    const float* ap = x + ((size_t)(b * DMODEL + d0 + (arow & 31))) * LSEQ + kc * 1024 + aoff;
    const u16* bp = ABu + ((size_t)(b * SDIM + arow)) * LSEQ + kc * 1024 + aoff;
    f32x4 acc[2];
    acc[0] = (f32x4){0.f, 0.f, 0.f, 0.f};
    acc[1] = (f32x4){0.f, 0.f, 0.f, 0.f};

    for (int ks = 0; ks < 1024; ks += 32) {
        if (t < 128) {
            float4 a0 = *reinterpret_cast<const float4*>(ap + ks);
            float4 a1 = *reinterpret_cast<const float4*>(ap + ks + 4);
            s16x8 av;
            av[0] = (short)f2b(a0.x); av[1] = (short)f2b(a0.y); av[2] = (short)f2b(a0.z); av[3] = (short)f2b(a0.w);
            av[4] = (short)f2b(a1.x); av[5] = (short)f2b(a1.y); av[6] = (short)f2b(a1.z); av[7] = (short)f2b(a1.w);
            *reinterpret_cast<s16x8*>(&As[arow * 40 + aoff]) = av;
        }
        s16x8 bv = *reinterpret_cast<const s16x8*>(bp + ks);
        *reinterpret_cast<s16x8*>(&Bs[arow * 40 + aoff]) = bv;
        __syncthreads();
        s16x8 af = *reinterpret_cast<s16x8*>(&As[(wm * 16 + lm) * 40 + kg * 8]);
        s16x8 bf0 = *reinterpret_cast<s16x8*>(&Bs[(wn * 32 + lm) * 40 + kg * 8]);
        s16x8 bf1 = *reinterpret_cast<s16x8*>(&Bs[(wn * 32 + 16 + lm) * 40 + kg * 8]);
        acc[0] = __builtin_amdgcn_mfma_f32_16x16x32_bf16(af, bf0, acc[0], 0, 0, 0);
        acc[1] = __builtin_amdgcn_mfma_f32_16x16x32_bf16(af, bf1, acc[1], 0, 0, 0);
        __syncthreads();
    }
    #pragma unroll
    for (int j = 0; j < 2; ++j) {
        int d = d0 + wm * 16 + kg * 4;
        int s = wn * 32 + j * 16 + lm;
        float* p = hpart + (size_t)kc * (1024 * DMODEL) + ((size_t)b * 64 + s) * DMODEL + d;
        *reinterpret_cast<f32x4*>(p) = acc[j];
    }
}

// ---------------- k4r: HTB[bs][d] = bf16(sum of 4 hpartT) ----------------
__global__ __launch_bounds__(256) void k4r(const float* __restrict__ hp,
                                           u16* __restrict__ htb) {
    const int i = (blockIdx.x * 256 + threadIdx.x) * 4;
    const int N = 1024 * DMODEL;
    float4 v0 = *reinterpret_cast<const float4*>(hp + i);
    float4 v1 = *reinterpret_cast<const float4*>(hp + N + i);
    float4 v2 = *reinterpret_cast<const float4*>(hp + 2 * N + i);
    float4 v3 = *reinterpret_cast<const float4*>(hp + 3 * N + i);
    ushort4 o;
    o.x = f2b(v0.x + v1.x + v2.x + v3.x);
    o.y = f2b(v0.y + v1.y + v2.y + v3.y);
    o.z = f2b(v0.z + v1.z + v2.z + v3.z);
    o.w = f2b(v0.w + v1.w + v2.w + v3.w);
    *reinterpret_cast<ushort4*>(htb + i) = o;
}

// ---------------- k5hz: HZT[bs][o] = HTB[bs][:] . Whz[o][:] (MFMA) ----------------
__global__ __launch_bounds__(256) void k5hz(const u16* __restrict__ HTB,
                                            const float* __restrict__ Whz,
                                            float* __restrict__ HZT) {
    __shared__ __align__(16) short As[64 * 40];
    __shared__ __align__(16) short Bs[64 * 40];
    const int t = threadIdx.x;
    const int m0 = blockIdx.x * 64;
    const int n0 = blockIdx.y * 64;
    const int lane = t & 63;
    const int w = t >> 6;
    const int wm = w >> 1, wn = w & 1;
    const int lm = lane & 15, kg = lane >> 4;
    const int arow = t >> 2;
    const int aoff = (t & 3) * 8;
    const u16* apg = HTB + (size_t)(m0 + arow) * DMODEL + aoff;
    const float* bpg = Whz + (size_t)(n0 + arow) * DMODEL + aoff;
    f32x4 acc[2][2];
    #pragma unroll
    for (int i = 0; i < 2; ++i)
        #pragma unroll
        for (int j = 0; j < 2; ++j) acc[i][j] = (f32x4){0.f, 0.f, 0.f, 0.f};

    for (int kc = 0; kc < DMODEL; kc += 32) {
        s16x8 av = *reinterpret_cast<const s16x8*>(apg + kc);
        float4 b0 = *reinterpret_cast<const float4*>(bpg + kc);
        float4 b1 = *reinterpret_cast<const float4*>(bpg + kc + 4);
        s16x8 bv;
        bv[0] = (short)f2b(b0.x); bv[1] = (short)f2b(b0.y); bv[2] = (short)f2b(b0.z); bv[3] = (short)f2b(b0.w);
        bv[4] = (short)f2b(b1.x); bv[5] = (short)f2b(b1.y); bv[6] = (short)f2b(b1.z); bv[7] = (short)f2b(b1.w);
        *reinterpret_cast<s16x8*>(&As[arow * 40 + aoff]) = av;
        *reinterpret_cast<s16x8*>(&Bs[arow * 40 + aoff]) = bv;
        __syncthreads();
        s16x8 af[2], bf[2];
        #pragma unroll
        for (int i = 0; i < 2; ++i) {
            af[i] = *reinterpret_cast<s16x8*>(&As[(wm * 32 + i * 16 + lm) * 40 + kg * 8]);
            bf[i] = *reinterpret_cast<s16x8*>(&Bs[(wn * 32 + i * 16 + lm) * 40 + kg * 8]);
        }
        #pragma unroll
        for (int i = 0; i < 2; ++i)
            #pragma unroll
            for (int j = 0; j < 2; ++j)
                acc[i][j] = __builtin_amdgcn_mfma_f32_16x16x32_bf16(af[i], bf[j], acc[i][j], 0, 0, 0);
        __syncthreads();
    }
    #pragma unroll
    for (int i = 0; i < 2; ++i) {
        #pragma unroll
        for (int j = 0; j < 2; ++j) {
            #pragma unroll
            for (int r = 0; r < 4; ++r) {
                int bs = m0 + wm * 32 + i * 16 + kg * 4 + r;
                int o = n0 + wn * 32 + j * 16 + lm;
                HZT[(size_t)bs * 768 + o] = acc[i][j][r];
            }
        }
    }
}

// ---------------- k5g: HGT[bs][d] = bf16(h1 * (silu(z) + D)) ----------------
__global__ __launch_bounds__(256) void k5g(const float* __restrict__ HZT,
                                           const float* __restrict__ Dp,
                                           u16* __restrict__ HGT) {
    const int i = (blockIdx.x * 256 + threadIdx.x) * 4;
    const int bs = i / DMODEL, d = i - bs * DMODEL;
    const float* p = HZT + (size_t)bs * 768 + d;
    float4 h1 = *reinterpret_cast<const float4*>(p);
    float4 z  = *reinterpret_cast<const float4*>(p + DMODEL);
    const float Dv = Dp[0];
    ushort4 o;
    o.x = f2b(h1.x * (z.x / (1.f + expf(-z.x)) + Dv));
    o.y = f2b(h1.y * (z.y / (1.f + expf(-z.y)) + Dv));
    o.z = f2b(h1.z * (z.z / (1.f + expf(-z.z)) + Dv));
    o.w = f2b(h1.w * (z.w / (1.f + expf(-z.w)) + Dv));
    *reinterpret_cast<ushort4*>(HGT + i) = o;
}

// ---------------- k5ho: hout = HGT . Wout^T (MFMA); writes ho f32 + hob bf16 -------
__global__ __launch_bounds__(256) void k5ho(const u16* __restrict__ HGT,
                                            const float* __restrict__ Wout,
                                            float* __restrict__ ho,
                                            u16* __restrict__ hob) {
    __shared__ __align__(16) short As[64 * 40];
    __shared__ __align__(16) short Bs[64 * 40];
    const int t = threadIdx.x;
    const int m0 = blockIdx.x * 64;
    const int n0 = blockIdx.y * 64;
    const int lane = t & 63;
    const int w = t >> 6;
    const int wm = w >> 1, wn = w & 1;
    const int lm = lane & 15, kg = lane >> 4;
    const int arow = t >> 2;
    const int aoff = (t & 3) * 8;
    const u16* apg = HGT + (size_t)(m0 + arow) * DMODEL + aoff;
    const float* bpg = Wout + (size_t)(n0 + arow) * DMODEL + aoff;
    f32x4 acc[2][2];
    #pragma unroll
    for (int i = 0; i < 2; ++i)
        #pragma unroll
        for (int j = 0; j < 2; ++j) acc[i][j] = (f32x4){0.f, 0.f, 0.f, 0.f};

    for (int kc = 0; kc < DMODEL; kc += 32) {
        s16x8 av = *reinterpret_cast<const s16x8*>(apg + kc);
        float4 b0 = *reinterpret_cast<const float4*>(bpg + kc);
        float4 b1 = *reinterpret_cast<const float4*>(bpg + kc + 4);
        s16x8 bv;
        bv[0] = (short)f2b(b0.x); bv[1] = (short)f2b(b0.y); bv[2] = (short)f2b(b0.z); bv[3] = (short)f2b(b0.w);
        bv[4] = (short)f2b(b1.x); bv[5] = (short)f2b(b1.y); bv[6] = (short)f2b(b1.z); bv[7] = (short)f2b(b1.w);
        *reinterpret_cast<s16x8*>(&As[arow * 40 + aoff]) = av;
        *reinterpret_cast<s16x8*>(&Bs[arow * 40 + aoff]) = bv;
        __syncthreads();
        s16x8 af[2], bf[2];
        #pragma unroll
        for (int i = 0; i < 2; ++i) {
            af[i] = *reinterpret_cast<s16x8*>(&As[(wm * 32 + i * 16 + lm) * 40 + kg * 8]);
            bf[i] = *reinterpret_cast<s16x8*>(&Bs[(wn * 32 + i * 16 + lm) * 40 + kg * 8]);
        }
        #pragma unroll
        for (int i = 0; i < 2; ++i)
            #pragma unroll
            for (int j = 0; j < 2; ++j)
                acc[i][j] = __builtin_amdgcn_mfma_f32_16x16x32_bf16(af[i], bf[j], acc[i][j], 0, 0, 0);
        __syncthreads();
    }
    #pragma unroll
    for (int i = 0; i < 2; ++i) {
        #pragma unroll
        for (int j = 0; j < 2; ++j) {
            int bs = m0 + wm * 32 + i * 16 + kg * 4;
            int b = bs >> 6, s = bs & 63;
            int o = n0 + wn * 32 + j * 16 + lm;
            size_t idx = ((size_t)b * DMODEL + o) * SDIM + s;
            *reinterpret_cast<f32x4*>(ho + idx) = acc[i][j];
            ushort4 u;
            u.x = f2b(acc[i][j][0]); u.y = f2b(acc[i][j][1]);
            u.z = f2b(acc[i][j][2]); u.w = f2b(acc[i][j][3]);
            *reinterpret_cast<ushort4*>(hob + idx) = u;
        }
    }
}

// ---------------- k6: y = hob x CmT (MFMA, no LDS) ----------------
__global__ __launch_bounds__(256) void k6_mfma(const u16* __restrict__ CmT,
                                               const u16* __restrict__ hob,
                                               float* __restrict__ y) {
    const int t = threadIdx.x;
    const int l0 = blockIdx.x * 128;
    const int d0 = blockIdx.y * 128;
    const int b = blockIdx.z;
    const int lane = t & 63;
    const int w = t >> 6;
    const int wm = w >> 1, wn = w & 1;
    const int lm = lane & 15, kg = lane >> 4;
    const u16* hp = hob + (size_t)b * DMODEL * SDIM;
    const u16* cp = CmT + (size_t)b * LSEQ * SDIM;
    s16x8 af[4][2], bf[4][2];
    #pragma unroll
    for (int i = 0; i < 4; ++i)
        #pragma unroll
        for (int ks = 0; ks < 2; ++ks)
            af[i][ks] = *reinterpret_cast<const s16x8*>(
                hp + (size_t)(d0 + wm * 64 + i * 16 + lm) * SDIM + ks * 32 + kg * 8);
    #pragma unroll
    for (int j = 0; j < 4; ++j)
        #pragma unroll
        for (int ks = 0; ks < 2; ++ks)
            bf[j][ks] = *reinterpret_cast<const s16x8*>(
                cp + (size_t)(l0 + wn * 64 + j * 16 + lm) * SDIM + ks * 32 + kg * 8);
    f32x4 acc[4][4];
    #pragma unroll
    for (int i = 0; i < 4; ++i)
        #pragma unroll
        for (int j = 0; j < 4; ++j) acc[i][j] = (f32x4){0.f, 0.f, 0.f, 0.f};
    #pragma unroll
    for (int ks = 0; ks < 2; ++ks)
        #pragma unroll
        for (int i = 0; i < 4; ++i)
            #pragma unroll
            for (int j = 0; j < 4; ++j)
                acc[i][j] = __builtin_amdgcn_mfma_f32_16x16x32_bf16(af[i][ks], bf[j][ks], acc[i][j], 0, 0, 0);
    float* yp = y + (size_t)b * DMODEL * LSEQ;
    #pragma unroll
    for (int i = 0; i < 4; ++i) {
        #pragma unroll
        for (int j = 0; j < 4; ++j) {
            #pragma unroll
            for (int r = 0; r < 4; ++r) {
                int d = d0 + wm * 64 + i * 16 + kg * 4 + r;
                int l = l0 + wn * 64 + j * 16 + lm;
                yp[(size_t)d * LSEQ + l] = acc[i][j][r];
            }
        }
    }
}

extern "C" void kernel_launch(void* const* d_in, const int* in_sizes, int n_in,
                              void* d_out, int out_size, void* d_ws, size_t ws_size,
                              hipStream_t stream) {
    const float* x    = (const float*)d_in[0];
    const float* Wb   = (const float*)d_in[1];
    const float* Wdw  = (const float*)d_in[2];
    const float* Whz  = (const float*)d_in[3];
    const float* Wout = (const float*)d_in[4];
    const float* Ap   = (const float*)d_in[5];
    const float* Dp   = (const float*)d_in[6];

    float* out = (float*)d_out;
    const size_t YSIZE = (size_t)NB * DMODEL * LSEQ;   // 25165824 floats

    // d_out y-region scratch (float offsets), all dead before k6 rewrites y:
    //   RAWB (u16) [0,        6291456)   bcdt all 192 ch bf16 (dead after k23)
    //   CMB  (u16) [8388608, 10485760)   bf16 Cm (written by k23)
    //   AB   (u16) [20971520, 23068672)  bf16 AB (dead after k4)
    //   Phase2 (reusing dead RAWB region, all after k23):
    //   HPART f32 [0, 1572864)        4 x [1024][384]
    //   HTB   u16 [1572864, 1769472)  [1024][384] bf16
    //   HZT   f32 [1769472, 2555904)  [1024][768]
    //   HGT   u16 [2555904, 2752512)  [1024][384] bf16
    // ws: CmT u16 [0, 4194304), HOB u16 [4194304, 4587520)
    u16*   RAWB   = (u16*)out;
    u16*   CMB    = (u16*)(out + 8388608);
    u16*   ABu    = (u16*)(out + 20971520);
    float* HPART  = out;
    u16*   HTB    = (u16*)(out + 1572864);
    float* HZT    = out + 1769472;
    u16*   HGT    = (u16*)(out + 2555904);
    float* HO     = out + YSIZE;       // hout output (f32)
    u16*   CmT    = (u16*)d_ws;
    u16*   HOB    = (u16*)d_ws + 4194304;

    k01_mfma<<<dim3(32, NB), 512, 0, stream>>>(x, Wb, RAWB);
    k23_ab  <<<dim3(SDIM, NB), 256, 0, stream>>>(RAWB, Wdw, Ap, ABu, CMB);
    kcmT    <<<dim3(64, NB), 256, 0, stream>>>(CMB, CmT);
    k4_mfma <<<dim3(12, 4, NB), 256, 0, stream>>>(x, ABu, HPART);
    k4r     <<<dim3(384), 256, 0, stream>>>(HPART, HTB);
    k5hz    <<<dim3(16, 12), 256, 0, stream>>>(HTB, Whz, HZT);
    k5g     <<<dim3(384), 256, 0, stream>>>(HZT, Dp, HGT);
    k5ho    <<<dim3(16, 6), 256, 0, stream>>>(HGT, Wout, HO, HOB);
    k6_mfma <<<dim3(32, 3, NB), 256, 0, stream>>>(CmT, HOB, out);
}